// Round 10
// baseline (548.308 us; speedup 1.0000x reference)
//
#include <hip/hip_runtime.h>

// Problem constants (G=1024 grid, known structure)
#define GSZ   1024
#define NV    (GSZ*GSZ)           // 1048576 vertices
#define N3    (NV*3)              // floats per [NV,3] array
#define FH    ((GSZ-1)*(GSZ-1))   // faces in first half
#define NF    (2*FH)              // total faces
#define O1    N3                  // centroid offset in d_out (floats)
#define O2    (O1 + 3*NF)         // fn offset
#define O3    (O2 + 3*NF)         // vn offset
#define LAM   10.0f
#define NFUSED 21                 // 21 fused x 3 steps -> x_64; vn err model 4.3e-3 (4.6x margin)

// Chebyshev interval for M = I + 10*L: lambda(L) in [0,9] exactly (stencil
// symbol 6-2cos a-2cos b-2cos(a-b) peaks at 9; free boundary <= infinite
// lattice by zero-extension). lambda(M) in [1,91]. Validated rounds 7-9.
#define CH_THETA 46.0
#define CH_DELTA 45.0

#define NTHR 256

typedef float f4u __attribute__((ext_vector_type(4), aligned(4)));

__device__ __forceinline__ void diag4(int i, int t, float dg[4]) {
  bool im = (i > 0), ip = (i < GSZ - 1);
#pragma unroll
  for (int k = 0; k < 4; ++k) {
    bool jm = (k > 0) || (t > 0);
    bool jp = (k < 3) || (t < 255);
    int deg = (int)jm + (int)jp + (int)im + (int)ip
            + (int)(ip && jm) + (int)(im && jp);
    dg[k] = 1.0f + LAM * (float)deg;
  }
}

// q = (A x)_row for the 4 cols of this thread, from register rows.
// Guards zero out-of-grid terms (self-healing trapezoid, validated r8/r9).
__device__ __forceinline__ void sten_q4(
    const float* up, const float* mid, const float* dn,
    float Lm, float Ld, float Rm, float Ru,
    int r, int t2, float q[4]) {
  bool im = (r > 0), ip = (r < GSZ - 1);
  bool jm = (t2 > 0), jp = (t2 < 255);
  float u0 = im ? up[0] : 0.f, u1 = im ? up[1] : 0.f;
  float u2 = im ? up[2] : 0.f, u3 = im ? up[3] : 0.f;
  float d0 = ip ? dn[0] : 0.f, d1 = ip ? dn[1] : 0.f;
  float d2 = ip ? dn[2] : 0.f, d3 = ip ? dn[3] : 0.f;
  float lm = jm ? Lm : 0.f, ld = (jm && ip) ? Ld : 0.f;
  float rm = jp ? Rm : 0.f, ru = (jp && im) ? Ru : 0.f;
  float dg[4]; diag4(r, t2, dg);
  q[0] = dg[0]*mid[0] - LAM*(lm     + mid[1] + u0 + d0 + ld + u1);
  q[1] = dg[1]*mid[1] - LAM*(mid[0] + mid[2] + u1 + d1 + d0 + u2);
  q[2] = dg[2]*mid[2] - LAM*(mid[1] + mid[3] + u2 + d2 + d1 + u3);
  q[3] = dg[3]*mid[3] - LAM*(mid[2] + rm     + u3 + d3 + d2 + ru);
}

// interleaved u -> one color's float4 at vtx..vtx+3
__device__ __forceinline__ float4 load_u_col(const float* __restrict__ u,
                                             int vtx, int col) {
  float4 a = *(const float4*)(u + 3 * vtx);
  float4 b = *(const float4*)(u + 3 * vtx + 4);
  float4 c = *(const float4*)(u + 3 * vtx + 8);
  if (col == 0) return make_float4(a.x, a.w, b.z, c.y);
  if (col == 1) return make_float4(a.y, b.x, b.w, c.z);
  return make_float4(a.z, b.y, c.x, c.w);
}

// =====================================================================
// Shared 3-level trapezoid body. XK, BB prepared by caller; pp supplied
// per-row by caller (zero for the first launch). Writes o2/o3 rows 3..6.
// =====================================================================
struct ChebState {
  float XK[10][4];
  float XKL[10], XKR[10];
  float BB[8][4];
  float PP[8][4];
};

__device__ __forceinline__ void cheb3_levels(ChebState& S,
    float* __restrict__ Op2, float* __restrict__ Op3,
    int r0, int t2, int lane, int wv, int j0,
    float c1a, float c2a, float c1b, float c2b, float c1c, float c2c,
    float eA0[4][8], float eA3[4][8], float eB0[4][6], float eB3[4][6]) {
  // ---- level 1: rows 1..8 ----
  float L1[10][4];
#pragma unroll
  for (int tr = 1; tr < 9; ++tr) {
    int r = r0 - 3 + tr;
    float q[4];
    sten_q4(S.XK[tr-1], S.XK[tr], S.XK[tr+1], S.XKL[tr], S.XKL[tr+1],
            S.XKR[tr], S.XKR[tr-1], r, t2, q);
#pragma unroll
    for (int k = 0; k < 4; ++k) {
      float m = S.XK[tr][k];
      L1[tr][k] = m + c1a * (m - S.PP[tr-1][k]) + c2a * (S.BB[tr-1][k] - q[k]);
    }
  }
  // L1 wave-edge exchange
  if (lane == 0) {
#pragma unroll
    for (int tr = 1; tr < 9; ++tr) eA0[wv][tr-1] = L1[tr][0];
  }
  if (lane == 63) {
#pragma unroll
    for (int tr = 1; tr < 9; ++tr) eA3[wv][tr-1] = L1[tr][3];
  }
  __syncthreads();
  float L1L[10], L1R[10];
#pragma unroll
  for (int tr = 1; tr < 9; ++tr) {
    L1R[tr] = __shfl_down(L1[tr][0], 1, 64);
    L1L[tr] = __shfl_up(L1[tr][3], 1, 64);
  }
  if (lane == 63) {
#pragma unroll
    for (int tr = 1; tr < 9; ++tr) L1R[tr] = (t2 < 255) ? eA0[wv + 1][tr-1] : 0.f;
  }
  if (lane == 0) {
#pragma unroll
    for (int tr = 1; tr < 9; ++tr) L1L[tr] = (t2 > 0) ? eA3[wv - 1][tr-1] : 0.f;
  }

  // ---- level 2: rows 2..7 ----
  float L2[10][4];
#pragma unroll
  for (int tr = 2; tr < 8; ++tr) {
    int r = r0 - 3 + tr;
    float q[4];
    sten_q4(L1[tr-1], L1[tr], L1[tr+1], L1L[tr], L1L[tr+1], L1R[tr], L1R[tr-1], r, t2, q);
#pragma unroll
    for (int k = 0; k < 4; ++k) {
      float m = L1[tr][k];
      L2[tr][k] = m + c1b * (m - S.XK[tr][k]) + c2b * (S.BB[tr-1][k] - q[k]);
    }
  }
  // L2 wave-edge exchange
  if (lane == 0) {
#pragma unroll
    for (int tr = 2; tr < 8; ++tr) eB0[wv][tr-2] = L2[tr][0];
  }
  if (lane == 63) {
#pragma unroll
    for (int tr = 2; tr < 8; ++tr) eB3[wv][tr-2] = L2[tr][3];
  }
  __syncthreads();
  float L2L[10], L2R[10];
#pragma unroll
  for (int tr = 2; tr < 8; ++tr) {
    L2R[tr] = __shfl_down(L2[tr][0], 1, 64);
    L2L[tr] = __shfl_up(L2[tr][3], 1, 64);
  }
  if (lane == 63) {
#pragma unroll
    for (int tr = 2; tr < 8; ++tr) L2R[tr] = (t2 < 255) ? eB0[wv + 1][tr-2] : 0.f;
  }
  if (lane == 0) {
#pragma unroll
    for (int tr = 2; tr < 8; ++tr) L2L[tr] = (t2 > 0) ? eB3[wv - 1][tr-2] : 0.f;
  }

  // ---- level 3 on output rows 3..6 + writes ----
#pragma unroll
  for (int tr = 3; tr < 7; ++tr) {
    int r = r0 - 3 + tr;
    float q[4];
    sten_q4(L2[tr-1], L2[tr], L2[tr+1], L2L[tr], L2L[tr+1], L2R[tr], L2R[tr-1], r, t2, q);
    float x3[4];
#pragma unroll
    for (int k = 0; k < 4; ++k) {
      float m = L2[tr][k];
      x3[k] = m + c1c * (m - L1[tr][k]) + c2c * (S.BB[tr-1][k] - q[k]);
    }
    *(float4*)(Op2 + r * GSZ + j0) = make_float4(L2[tr][0], L2[tr][1], L2[tr][2], L2[tr][3]);
    *(float4*)(Op3 + r * GSZ + j0) = make_float4(x3[0], x3[1], x3[2], x3[3]);
  }
}

// ---------- steady-state fused 3-step (reads xs stencil, xp pointwise, b) ----------
__global__ __launch_bounds__(256, 3) void k_cheb3(
    const float* __restrict__ xs, const float* __restrict__ xp,
    float* __restrict__ o2, float* __restrict__ o3,
    const float* __restrict__ bpl,
    float c1a, float c2a, float c1b, float c2b, float c1c, float c2c) {
  int tile = blockIdx.x & 255;
  int col  = blockIdx.x >> 8;
  int t2 = threadIdx.x;
  int lane = t2 & 63;
  int wv = t2 >> 6;
  int r0 = ((tile & 7) << 7) + ((tile >> 3) << 2);
  int j0 = t2 << 2;

  const float* XS = xs  + col * NV;
  const float* XP = xp  + col * NV;
  const float* BP = bpl + col * NV;
  float* Op2 = o2 + col * NV;
  float* Op3 = o3 + col * NV;

  __shared__ float eA0[4][8], eA3[4][8];
  __shared__ float eB0[4][6], eB3[4][6];

  ChebState S;
#pragma unroll
  for (int tr = 0; tr < 10; ++tr) {
    int r = r0 - 3 + tr;
    if (r >= 0 && r < GSZ) {
      float4 v = *(const float4*)(XS + r * GSZ + j0);
      S.XK[tr][0]=v.x; S.XK[tr][1]=v.y; S.XK[tr][2]=v.z; S.XK[tr][3]=v.w;
    } else { S.XK[tr][0]=0.f; S.XK[tr][1]=0.f; S.XK[tr][2]=0.f; S.XK[tr][3]=0.f; }
  }
#pragma unroll
  for (int tr = 0; tr < 10; ++tr) {
    S.XKR[tr] = __shfl_down(S.XK[tr][0], 1, 64);
    S.XKL[tr] = __shfl_up(S.XK[tr][3], 1, 64);
  }
  if (lane == 63) {
#pragma unroll
    for (int tr = 0; tr < 10; ++tr) {
      int r = r0 - 3 + tr;
      S.XKR[tr] = (t2 < 255 && r >= 0 && r < GSZ) ? XS[r * GSZ + j0 + 4] : 0.f;
    }
  }
  if (lane == 0) {
#pragma unroll
    for (int tr = 0; tr < 10; ++tr) {
      int r = r0 - 3 + tr;
      S.XKL[tr] = (t2 > 0 && r >= 0 && r < GSZ) ? XS[r * GSZ + j0 - 1] : 0.f;
    }
  }
#pragma unroll
  for (int tr = 1; tr < 9; ++tr) {
    int r = r0 - 3 + tr;
    bool v = (r >= 0 && r < GSZ);
    float4 bv = v ? *(const float4*)(BP + r * GSZ + j0) : make_float4(0.f,0.f,0.f,0.f);
    float4 pv = v ? *(const float4*)(XP + r * GSZ + j0) : make_float4(0.f,0.f,0.f,0.f);
    S.BB[tr-1][0]=bv.x; S.BB[tr-1][1]=bv.y; S.BB[tr-1][2]=bv.z; S.BB[tr-1][3]=bv.w;
    S.PP[tr-1][0]=pv.x; S.PP[tr-1][1]=pv.y; S.PP[tr-1][2]=pv.z; S.PP[tr-1][3]=pv.w;
  }
  cheb3_levels(S, Op2, Op3, r0, t2, lane, wv, j0,
               c1a, c2a, c1b, c2b, c1c, c2c, eA0, eA3, eB0, eB3);
}

// ---------- first fused launch: reads u directly; x0=0, x1=b/theta ----------
// Also writes the b planes (own output rows) for subsequent launches.
__global__ __launch_bounds__(256, 3) void k_cheb3_first(
    const float* __restrict__ u,
    float* __restrict__ o2, float* __restrict__ o3,
    float* __restrict__ bpl,
    float c1a, float c2a, float c1b, float c2b, float c1c, float c2c) {
  int tile = blockIdx.x & 255;
  int col  = blockIdx.x >> 8;
  int t2 = threadIdx.x;
  int lane = t2 & 63;
  int wv = t2 >> 6;
  int r0 = ((tile & 7) << 7) + ((tile >> 3) << 2);
  int j0 = t2 << 2;

  float* BPo = bpl + col * NV;
  float* Op2 = o2 + col * NV;
  float* Op3 = o3 + col * NV;
  const float invth = (float)(1.0 / CH_THETA);

  __shared__ float eA0[4][8], eA3[4][8];
  __shared__ float eB0[4][6], eB3[4][6];

  ChebState S;
#pragma unroll
  for (int tr = 0; tr < 10; ++tr) {
    int r = r0 - 3 + tr;
    float4 raw = (r >= 0 && r < GSZ) ? load_u_col(u, r * GSZ + j0, col)
                                     : make_float4(0.f,0.f,0.f,0.f);
    if (tr >= 1 && tr <= 8) {
      S.BB[tr-1][0]=raw.x; S.BB[tr-1][1]=raw.y; S.BB[tr-1][2]=raw.z; S.BB[tr-1][3]=raw.w;
      S.PP[tr-1][0]=0.f;   S.PP[tr-1][1]=0.f;   S.PP[tr-1][2]=0.f;   S.PP[tr-1][3]=0.f;
    }
    S.XK[tr][0]=raw.x*invth; S.XK[tr][1]=raw.y*invth;
    S.XK[tr][2]=raw.z*invth; S.XK[tr][3]=raw.w*invth;
    if (tr >= 3 && tr < 7)       // write b plane for own output rows
      *(float4*)(BPo + r * GSZ + j0) = raw;
  }
#pragma unroll
  for (int tr = 0; tr < 10; ++tr) {
    S.XKR[tr] = __shfl_down(S.XK[tr][0], 1, 64);
    S.XKL[tr] = __shfl_up(S.XK[tr][3], 1, 64);
  }
  if (lane == 63) {
#pragma unroll
    for (int tr = 0; tr < 10; ++tr) {
      int r = r0 - 3 + tr;
      S.XKR[tr] = (t2 < 255 && r >= 0 && r < GSZ)
                ? u[3 * (r * GSZ + j0 + 4) + col] * invth : 0.f;
    }
  }
  if (lane == 0) {
#pragma unroll
    for (int tr = 0; tr < 10; ++tr) {
      int r = r0 - 3 + tr;
      S.XKL[tr] = (t2 > 0 && r >= 0 && r < GSZ)
                ? u[3 * (r * GSZ + j0 - 1) + col] * invth : 0.f;
    }
  }
  cheb3_levels(S, Op2, Op3, r0, t2, lane, wv, j0,
               c1a, c2a, c1b, c2b, c1c, c2c, eA0, eA3, eB0, eB3);
}

// ---------- faces + verts: read x planes; write verts, centroid, fn ----------
__device__ __forceinline__ void face_cf(float t0x, float t0y, float t0z,
    float t1x, float t1y, float t1z, float b0x, float b0y, float b0z,
    float* cen, float* fnv) {
  const float third = 1.0f / 3.0f;
  cen[0] = (t0x + t1x + b0x) * third;
  cen[1] = (t0y + t1y + b0y) * third;
  cen[2] = (t0z + t1z + b0z) * third;
  float ax = t1x - t0x, ay = t1y - t0y, az = t1z - t0z;
  float bx = b0x - t0x, by = b0y - t0y, bz = b0z - t0z;
  float cx = ay * bz - az * by;
  float cy = az * bx - ax * bz;
  float cz = ax * by - ay * bx;
  float inv = 1.0f / fmaxf(sqrtf(cx * cx + cy * cy + cz * cz), 1e-12f);
  fnv[0] = cx * inv; fnv[1] = cy * inv; fnv[2] = cz * inv;
}

// 5th column via guarded scalar load (round-4 lesson: no divergent shuffles).
__global__ __launch_bounds__(NTHR) void k_facesverts(const float* __restrict__ xp,
    float* __restrict__ verts, float* __restrict__ cen, float* __restrict__ fn) {
  int ci = blockIdx.x;           // 0..1022
  int t  = threadIdx.x;
  const float* Ps[3] = { xp, xp + NV, xp + 2 * NV };
  int c0 = t << 2;
  int bT = (ci << 10) + c0, bB = bT + GSZ;
  bool full = (t < 255);
  float T[3][5], B[3][5];
#pragma unroll
  for (int p = 0; p < 3; ++p) {
    float4 a = *(const float4*)(Ps[p] + bT);
    T[p][0] = a.x; T[p][1] = a.y; T[p][2] = a.z; T[p][3] = a.w;
    T[p][4] = full ? Ps[p][bT + 4] : 0.f;
    float4 b = *(const float4*)(Ps[p] + bB);
    B[p][0] = b.x; B[p][1] = b.y; B[p][2] = b.z; B[p][3] = b.w;
    B[p][4] = full ? Ps[p][bB + 4] : 0.f;
  }
  // verts row ci (all 256 threads full width); block 1022 also writes row 1023
  {
    int vtx = bT;
    *(float4*)(verts + 3 * vtx)     = make_float4(T[0][0], T[1][0], T[2][0], T[0][1]);
    *(float4*)(verts + 3 * vtx + 4) = make_float4(T[1][1], T[2][1], T[0][2], T[1][2]);
    *(float4*)(verts + 3 * vtx + 8) = make_float4(T[2][2], T[0][3], T[1][3], T[2][3]);
    if (ci == GSZ - 2) {
      int v2 = bB;
      *(float4*)(verts + 3 * v2)     = make_float4(B[0][0], B[1][0], B[2][0], B[0][1]);
      *(float4*)(verts + 3 * v2 + 4) = make_float4(B[1][1], B[2][1], B[0][2], B[1][2]);
      *(float4*)(verts + 3 * v2 + 8) = make_float4(B[2][2], B[0][3], B[1][3], B[2][3]);
    }
  }
  float c1[12], f1[12], c2[12], f2[12];
#pragma unroll
  for (int k = 0; k < 4; ++k) {
    face_cf(T[0][k], T[1][k], T[2][k], T[0][k+1], T[1][k+1], T[2][k+1],
            B[0][k], B[1][k], B[2][k], &c1[3*k], &f1[3*k]);
    face_cf(T[0][k+1], T[1][k+1], T[2][k+1], B[0][k+1], B[1][k+1], B[2][k+1],
            B[0][k], B[1][k], B[2][k], &c2[3*k], &f2[3*k]);
  }
  size_t fb1 = 3 * ((size_t)ci * (GSZ - 1) + c0);
  size_t fb2 = fb1 + 3 * (size_t)FH;
  if (full) {
#pragma unroll
    for (int w = 0; w < 3; ++w) {
      *(f4u*)(cen + fb1 + 4*w) = (f4u){ c1[4*w], c1[4*w+1], c1[4*w+2], c1[4*w+3] };
      *(f4u*)(fn  + fb1 + 4*w) = (f4u){ f1[4*w], f1[4*w+1], f1[4*w+2], f1[4*w+3] };
      *(f4u*)(cen + fb2 + 4*w) = (f4u){ c2[4*w], c2[4*w+1], c2[4*w+2], c2[4*w+3] };
      *(f4u*)(fn  + fb2 + 4*w) = (f4u){ f2[4*w], f2[4*w+1], f2[4*w+2], f2[4*w+3] };
    }
  } else {
    for (int e = 0; e < 9; ++e) {
      cen[fb1 + e] = c1[e]; fn[fb1 + e] = f1[e];
      cen[fb2 + e] = c2[e]; fn[fb2 + e] = f2[e];
    }
  }
}

// ---------- per-vertex normal: gather <=6 adjacent faces ----------
__global__ __launch_bounds__(256) void k_vn(const float* __restrict__ fn,
    float* __restrict__ vn) {
  int t = blockIdx.x * 256 + threadIdx.x;
  int i = t >> 10, j = t & (GSZ - 1);
  float s0 = 0.f, s1 = 0.f, s2 = 0.f;
  bool iN = (i >= 1), iS = (i <= GSZ-2), jW = (j >= 1), jE = (j <= GSZ-2);
  int rowi = i * (GSZ-1);
#define ADD(fidx) { int f_ = (fidx); s0 += fn[3*f_]; s1 += fn[3*f_+1]; s2 += fn[3*f_+2]; }
  if (iS && jE) ADD(rowi + j);
  if (iS && jW) ADD(rowi + j - 1);
  if (iN && jE) ADD(rowi - (GSZ-1) + j);
  if (iS && jW) ADD(FH + rowi + j - 1);
  if (iN && jW) ADD(FH + rowi - (GSZ-1) + j - 1);
  if (iN && jE) ADD(FH + rowi - (GSZ-1) + j);
#undef ADD
  float nrm = sqrtf(s0*s0 + s1*s1 + s2*s2);
  float inv = 1.0f / fmaxf(nrm, 1e-12f);
  vn[3*t] = s0*inv; vn[3*t+1] = s1*inv; vn[3*t+2] = s2*inv;
}

extern "C" void kernel_launch(void* const* d_in, const int* in_sizes, int n_in,
                              void* d_out, int out_size, void* d_ws, size_t ws_size,
                              hipStream_t stream) {
  const float* u = (const float*)d_in[0];
  float* out = (float*)d_out;

  float* verts = out;
  float* cen   = out + O1;
  float* fn    = out + O2;
  float* vn    = out + O3;

  // Scratch (all disjoint):
  //   Aa  = verts region [0,3NV)  — scratch until k_facesverts writes verts
  //   bpl = [O1, O1+3NV), Bb = [O1+3NV, O1+6NV), Cc = [O1+6NV, O1+9NV)
  //         (inside cen+fn regions, 9NV < 6NF; clobbered by k_facesverts)
  //   Dv  = vn region [O3, O3+3NV) — final x lands here, k_vn overwrites last
  float* Aa  = out;
  float* bpl = out + O1;
  float* Bb  = out + O1 + 3 * (size_t)NV;
  float* Cc  = out + O1 + 6 * (size_t)NV;
  float* Dv  = out + O3;

  // Chebyshev, host-precomputed coefficients, 3 steps/launch.
  // Launch j: reads (x_{3j} pointwise, x_{3j+1} stencil), writes (x_{3j+3}, x_{3j+4}).
  // Parity chosen so the LAST launch writes (Cc, Dv): p=(NFUSED-1-j)&1;
  // p==0 -> read (Aa,Bb) write (Cc,Dv); p==1 -> read (Cc,Dv) write (Aa,Bb).
  // j=0 is the folded-init variant (reads u; also writes bpl).
  double s1 = CH_THETA / CH_DELTA;
  double rho_p = 1.0 / s1;
  float cc[6];
  int ci = 0, j = 0;
  for (int k = 1; k <= 3 * NFUSED; ++k) {
    double rho = 1.0 / (2.0 * s1 - rho_p);
    cc[2*ci]   = (float)(rho * rho_p);
    cc[2*ci+1] = (float)(2.0 * rho / CH_DELTA);
    rho_p = rho;
    if (++ci == 3) {
      int p = (NFUSED - 1 - j) & 1;
      float* o2_ = p ? Aa : Cc;
      float* o3_ = p ? Bb : Dv;
      if (j == 0) {
        k_cheb3_first<<<dim3(768), dim3(256), 0, stream>>>(u, o2_, o3_, bpl,
            cc[0], cc[1], cc[2], cc[3], cc[4], cc[5]);
      } else {
        const float* xp_ = p ? Cc : Aa;
        const float* xs_ = p ? Dv : Bb;
        k_cheb3<<<dim3(768), dim3(256), 0, stream>>>(xs_, xp_, o2_, o3_, bpl,
            cc[0], cc[1], cc[2], cc[3], cc[4], cc[5]);
      }
      ci = 0; ++j;
    }
  }
  // NFUSED=21 odd: j=0 has p=0 -> writes (Cc,Dv); chain alternates; last
  // launch j=20 has p=0 -> final x_64 in Dv.

  k_facesverts<<<dim3(GSZ - 1), dim3(NTHR), 0, stream>>>(Dv, verts, cen, fn);
  k_vn<<<dim3(NV / 256), dim3(256), 0, stream>>>(fn, vn);
}

// Round 11
// 448.326 us; speedup vs baseline: 1.2230x; 1.2230x over previous
//
#include <hip/hip_runtime.h>

// Problem constants (G=1024 grid, known structure)
#define GSZ   1024
#define NV    (GSZ*GSZ)           // 1048576 vertices
#define N3    (NV*3)              // floats per [NV,3] array
#define FH    ((GSZ-1)*(GSZ-1))   // faces in first half
#define NF    (2*FH)              // total faces
#define O1    N3                  // centroid offset in d_out (floats)
#define O2    (O1 + 3*NF)         // fn offset
#define O3    (O2 + 3*NF)         // vn offset
#define LAM   10.0f
#define NFUSED 21                 // 21 fused x 3 steps -> x_64

// Chebyshev interval for M = I + 10*L: lambda(L) in [0,9] exactly.
// lambda(M) in [1,91]. Validated rounds 7-10.
#define CH_THETA 46.0
#define CH_DELTA 45.0

#define NTHR 256

typedef float f4u __attribute__((ext_vector_type(4), aligned(4)));

__device__ __forceinline__ void diag4(int i, int t, float dg[4]) {
  bool im = (i > 0), ip = (i < GSZ - 1);
#pragma unroll
  for (int k = 0; k < 4; ++k) {
    bool jm = (k > 0) || (t > 0);
    bool jp = (k < 3) || (t < 255);
    int deg = (int)jm + (int)jp + (int)im + (int)ip
            + (int)(ip && jm) + (int)(im && jp);
    dg[k] = 1.0f + LAM * (float)deg;
  }
}

// q = (A x)_row for the 4 cols of this thread (guards zero out-of-grid terms;
// self-healing trapezoid validated r8/r9).
__device__ __forceinline__ void sten_q4(
    const float* up, const float* mid, const float* dn,
    float Lm, float Ld, float Rm, float Ru,
    int r, int t2, float q[4]) {
  bool im = (r > 0), ip = (r < GSZ - 1);
  bool jm = (t2 > 0), jp = (t2 < 255);
  float u0 = im ? up[0] : 0.f, u1 = im ? up[1] : 0.f;
  float u2 = im ? up[2] : 0.f, u3 = im ? up[3] : 0.f;
  float d0 = ip ? dn[0] : 0.f, d1 = ip ? dn[1] : 0.f;
  float d2 = ip ? dn[2] : 0.f, d3 = ip ? dn[3] : 0.f;
  float lm = jm ? Lm : 0.f, ld = (jm && ip) ? Ld : 0.f;
  float rm = jp ? Rm : 0.f, ru = (jp && im) ? Ru : 0.f;
  float dg[4]; diag4(r, t2, dg);
  q[0] = dg[0]*mid[0] - LAM*(lm     + mid[1] + u0 + d0 + ld + u1);
  q[1] = dg[1]*mid[1] - LAM*(mid[0] + mid[2] + u1 + d1 + d0 + u2);
  q[2] = dg[2]*mid[2] - LAM*(mid[1] + mid[3] + u2 + d2 + d1 + u3);
  q[3] = dg[3]*mid[3] - LAM*(mid[2] + rm     + u3 + d3 + d2 + ru);
}

// interleaved u -> one color's float4 at vtx..vtx+3
__device__ __forceinline__ float4 load_u_col(const float* __restrict__ u,
                                             int vtx, int col) {
  float4 a = *(const float4*)(u + 3 * vtx);
  float4 b = *(const float4*)(u + 3 * vtx + 4);
  float4 c = *(const float4*)(u + 3 * vtx + 8);
  if (col == 0) return make_float4(a.x, a.w, b.z, c.y);
  if (col == 1) return make_float4(a.y, b.x, b.w, c.z);
  return make_float4(a.z, b.y, c.x, c.w);
}

// ---------- steady-state fused 3-step (round-9 body, proven 18.9 us) ----------
// Reads x_k (stencil, 10 rows), x_{k-1} (pointwise, consumed on the fly),
// b (register-cached rows 1..8). Writes L2 -> o2, L3 -> o3 on rows 3..6.
__global__ __launch_bounds__(256, 3) void k_cheb3(
    const float* __restrict__ xs, const float* __restrict__ xp,
    float* __restrict__ o2, float* __restrict__ o3,
    const float* __restrict__ bpl,
    float c1a, float c2a, float c1b, float c2b, float c1c, float c2c) {
  int tile = blockIdx.x & 255;
  int col  = blockIdx.x >> 8;            // 0..2
  int t2 = threadIdx.x;
  int lane = t2 & 63;
  int wv = t2 >> 6;                      // wave 0..3
  int r0 = ((tile & 7) << 7) + ((tile >> 3) << 2);   // output rows [r0, r0+4)
  int j0 = t2 << 2;

  const float* XS = xs  + col * NV;
  const float* XP = xp  + col * NV;
  const float* BP = bpl + col * NV;
  float* Op2 = o2 + col * NV;
  float* Op3 = o3 + col * NV;

  __shared__ float eA0[4][8], eA3[4][8];   // L1 wave-edge cols, rows 1..8
  __shared__ float eB0[4][6], eB3[4][6];   // L2 wave-edge cols, rows 2..7

  // ---- load x_k tile ----
  float XK[10][4];
#pragma unroll
  for (int tr = 0; tr < 10; ++tr) {
    int r = r0 - 3 + tr;
    if (r >= 0 && r < GSZ) {
      float4 v = *(const float4*)(XS + r * GSZ + j0);
      XK[tr][0]=v.x; XK[tr][1]=v.y; XK[tr][2]=v.z; XK[tr][3]=v.w;
    } else { XK[tr][0]=0.f; XK[tr][1]=0.f; XK[tr][2]=0.f; XK[tr][3]=0.f; }
  }
  float XKL[10], XKR[10];
#pragma unroll
  for (int tr = 0; tr < 10; ++tr) {
    XKR[tr] = __shfl_down(XK[tr][0], 1, 64);
    XKL[tr] = __shfl_up(XK[tr][3], 1, 64);
  }
  if (lane == 63) {
#pragma unroll
    for (int tr = 0; tr < 10; ++tr) {
      int r = r0 - 3 + tr;
      XKR[tr] = (t2 < 255 && r >= 0 && r < GSZ) ? XS[r * GSZ + j0 + 4] : 0.f;
    }
  }
  if (lane == 0) {
#pragma unroll
    for (int tr = 0; tr < 10; ++tr) {
      int r = r0 - 3 + tr;
      XKL[tr] = (t2 > 0 && r >= 0 && r < GSZ) ? XS[r * GSZ + j0 - 1] : 0.f;
    }
  }

  // ---- level 1: rows 1..8; b cached in BB; x_{k-1} consumed on the fly ----
  float L1[10][4];
  float BB[8][4];
#pragma unroll
  for (int tr = 1; tr < 9; ++tr) {
    int r = r0 - 3 + tr;
    float q[4];
    sten_q4(XK[tr-1], XK[tr], XK[tr+1], XKL[tr], XKL[tr+1], XKR[tr], XKR[tr-1], r, t2, q);
    bool v = (r >= 0 && r < GSZ);
    float4 bv = v ? *(const float4*)(BP + r * GSZ + j0) : make_float4(0.f,0.f,0.f,0.f);
    float4 pv = v ? *(const float4*)(XP + r * GSZ + j0) : make_float4(0.f,0.f,0.f,0.f);
    BB[tr-1][0] = bv.x; BB[tr-1][1] = bv.y; BB[tr-1][2] = bv.z; BB[tr-1][3] = bv.w;
    float pp[4] = {pv.x, pv.y, pv.z, pv.w};
#pragma unroll
    for (int k = 0; k < 4; ++k) {
      float m = XK[tr][k];
      L1[tr][k] = m + c1a * (m - pp[k]) + c2a * (BB[tr-1][k] - q[k]);
    }
  }
  // L1 wave-edge exchange
  if (lane == 0) {
#pragma unroll
    for (int tr = 1; tr < 9; ++tr) eA0[wv][tr-1] = L1[tr][0];
  }
  if (lane == 63) {
#pragma unroll
    for (int tr = 1; tr < 9; ++tr) eA3[wv][tr-1] = L1[tr][3];
  }
  __syncthreads();
  float L1L[10], L1R[10];
#pragma unroll
  for (int tr = 1; tr < 9; ++tr) {
    L1R[tr] = __shfl_down(L1[tr][0], 1, 64);
    L1L[tr] = __shfl_up(L1[tr][3], 1, 64);
  }
  if (lane == 63) {
#pragma unroll
    for (int tr = 1; tr < 9; ++tr) L1R[tr] = (t2 < 255) ? eA0[wv + 1][tr-1] : 0.f;
  }
  if (lane == 0) {
#pragma unroll
    for (int tr = 1; tr < 9; ++tr) L1L[tr] = (t2 > 0) ? eA3[wv - 1][tr-1] : 0.f;
  }

  // ---- level 2: rows 2..7 ----
  float L2[10][4];
#pragma unroll
  for (int tr = 2; tr < 8; ++tr) {
    int r = r0 - 3 + tr;
    float q[4];
    sten_q4(L1[tr-1], L1[tr], L1[tr+1], L1L[tr], L1L[tr+1], L1R[tr], L1R[tr-1], r, t2, q);
#pragma unroll
    for (int k = 0; k < 4; ++k) {
      float m = L1[tr][k];
      L2[tr][k] = m + c1b * (m - XK[tr][k]) + c2b * (BB[tr-1][k] - q[k]);
    }
  }
  // L2 wave-edge exchange
  if (lane == 0) {
#pragma unroll
    for (int tr = 2; tr < 8; ++tr) eB0[wv][tr-2] = L2[tr][0];
  }
  if (lane == 63) {
#pragma unroll
    for (int tr = 2; tr < 8; ++tr) eB3[wv][tr-2] = L2[tr][3];
  }
  __syncthreads();
  float L2L[10], L2R[10];
#pragma unroll
  for (int tr = 2; tr < 8; ++tr) {
    L2R[tr] = __shfl_down(L2[tr][0], 1, 64);
    L2L[tr] = __shfl_up(L2[tr][3], 1, 64);
  }
  if (lane == 63) {
#pragma unroll
    for (int tr = 2; tr < 8; ++tr) L2R[tr] = (t2 < 255) ? eB0[wv + 1][tr-2] : 0.f;
  }
  if (lane == 0) {
#pragma unroll
    for (int tr = 2; tr < 8; ++tr) L2L[tr] = (t2 > 0) ? eB3[wv - 1][tr-2] : 0.f;
  }

  // ---- level 3 on output rows 3..6 + writes ----
#pragma unroll
  for (int tr = 3; tr < 7; ++tr) {
    int r = r0 - 3 + tr;
    float q[4];
    sten_q4(L2[tr-1], L2[tr], L2[tr+1], L2L[tr], L2L[tr+1], L2R[tr], L2R[tr-1], r, t2, q);
    float x3[4];
#pragma unroll
    for (int k = 0; k < 4; ++k) {
      float m = L2[tr][k];
      x3[k] = m + c1c * (m - L1[tr][k]) + c2c * (BB[tr-1][k] - q[k]);
    }
    *(float4*)(Op2 + r * GSZ + j0) = make_float4(L2[tr][0], L2[tr][1], L2[tr][2], L2[tr][3]);
    *(float4*)(Op3 + r * GSZ + j0) = make_float4(x3[0], x3[1], x3[2], x3[3]);
  }
}

// ---------- first fused launch: reads u; x0=0, x1=b/theta; writes bpl ----------
// Same register discipline as k_cheb3 (no PP array; x0 terms folded to 0).
__global__ __launch_bounds__(256, 3) void k_cheb3_first(
    const float* __restrict__ u,
    float* __restrict__ o2, float* __restrict__ o3,
    float* __restrict__ bpl,
    float c1a, float c2a, float c1b, float c2b, float c1c, float c2c) {
  int tile = blockIdx.x & 255;
  int col  = blockIdx.x >> 8;
  int t2 = threadIdx.x;
  int lane = t2 & 63;
  int wv = t2 >> 6;
  int r0 = ((tile & 7) << 7) + ((tile >> 3) << 2);
  int j0 = t2 << 2;

  float* BPo = bpl + col * NV;
  float* Op2 = o2 + col * NV;
  float* Op3 = o3 + col * NV;
  const float invth = (float)(1.0 / CH_THETA);

  __shared__ float eA0[4][8], eA3[4][8];
  __shared__ float eB0[4][6], eB3[4][6];

  // ---- load x1 = u/theta tile; BB filled in level-1 loop ----
  float XK[10][4];
#pragma unroll
  for (int tr = 0; tr < 10; ++tr) {
    int r = r0 - 3 + tr;
    if (r >= 0 && r < GSZ) {
      float4 raw = load_u_col(u, r * GSZ + j0, col);
      XK[tr][0]=raw.x*invth; XK[tr][1]=raw.y*invth;
      XK[tr][2]=raw.z*invth; XK[tr][3]=raw.w*invth;
    } else { XK[tr][0]=0.f; XK[tr][1]=0.f; XK[tr][2]=0.f; XK[tr][3]=0.f; }
  }
  float XKL[10], XKR[10];
#pragma unroll
  for (int tr = 0; tr < 10; ++tr) {
    XKR[tr] = __shfl_down(XK[tr][0], 1, 64);
    XKL[tr] = __shfl_up(XK[tr][3], 1, 64);
  }
  if (lane == 63) {
#pragma unroll
    for (int tr = 0; tr < 10; ++tr) {
      int r = r0 - 3 + tr;
      XKR[tr] = (t2 < 255 && r >= 0 && r < GSZ)
              ? u[3 * (r * GSZ + j0 + 4) + col] * invth : 0.f;
    }
  }
  if (lane == 0) {
#pragma unroll
    for (int tr = 0; tr < 10; ++tr) {
      int r = r0 - 3 + tr;
      XKL[tr] = (t2 > 0 && r >= 0 && r < GSZ)
              ? u[3 * (r * GSZ + j0 - 1) + col] * invth : 0.f;
    }
  }

  // ---- level 1: rows 1..8; b = theta * x1 (re-derived, avoids 2nd u read);
  //      x0 = 0 so the c1a term is just c1a*m ----
  const float thf = (float)CH_THETA;
  float L1[10][4];
  float BB[8][4];
#pragma unroll
  for (int tr = 1; tr < 9; ++tr) {
    int r = r0 - 3 + tr;
    float q[4];
    sten_q4(XK[tr-1], XK[tr], XK[tr+1], XKL[tr], XKL[tr+1], XKR[tr], XKR[tr-1], r, t2, q);
#pragma unroll
    for (int k = 0; k < 4; ++k) {
      float m = XK[tr][k];
      BB[tr-1][k] = m * thf;
      L1[tr][k] = m + c1a * m + c2a * (BB[tr-1][k] - q[k]);
    }
    if (tr >= 3 && tr < 7)    // publish b rows 3..6 (this block's output rows)
      *(float4*)(BPo + r * GSZ + j0) =
          make_float4(BB[tr-1][0], BB[tr-1][1], BB[tr-1][2], BB[tr-1][3]);
  }
  // L1 wave-edge exchange
  if (lane == 0) {
#pragma unroll
    for (int tr = 1; tr < 9; ++tr) eA0[wv][tr-1] = L1[tr][0];
  }
  if (lane == 63) {
#pragma unroll
    for (int tr = 1; tr < 9; ++tr) eA3[wv][tr-1] = L1[tr][3];
  }
  __syncthreads();
  float L1L[10], L1R[10];
#pragma unroll
  for (int tr = 1; tr < 9; ++tr) {
    L1R[tr] = __shfl_down(L1[tr][0], 1, 64);
    L1L[tr] = __shfl_up(L1[tr][3], 1, 64);
  }
  if (lane == 63) {
#pragma unroll
    for (int tr = 1; tr < 9; ++tr) L1R[tr] = (t2 < 255) ? eA0[wv + 1][tr-1] : 0.f;
  }
  if (lane == 0) {
#pragma unroll
    for (int tr = 1; tr < 9; ++tr) L1L[tr] = (t2 > 0) ? eA3[wv - 1][tr-1] : 0.f;
  }

  // ---- level 2: rows 2..7 ----
  float L2[10][4];
#pragma unroll
  for (int tr = 2; tr < 8; ++tr) {
    int r = r0 - 3 + tr;
    float q[4];
    sten_q4(L1[tr-1], L1[tr], L1[tr+1], L1L[tr], L1L[tr+1], L1R[tr], L1R[tr-1], r, t2, q);
#pragma unroll
    for (int k = 0; k < 4; ++k) {
      float m = L1[tr][k];
      L2[tr][k] = m + c1b * (m - XK[tr][k]) + c2b * (BB[tr-1][k] - q[k]);
    }
  }
  // L2 wave-edge exchange
  if (lane == 0) {
#pragma unroll
    for (int tr = 2; tr < 8; ++tr) eB0[wv][tr-2] = L2[tr][0];
  }
  if (lane == 63) {
#pragma unroll
    for (int tr = 2; tr < 8; ++tr) eB3[wv][tr-2] = L2[tr][3];
  }
  __syncthreads();
  float L2L[10], L2R[10];
#pragma unroll
  for (int tr = 2; tr < 8; ++tr) {
    L2R[tr] = __shfl_down(L2[tr][0], 1, 64);
    L2L[tr] = __shfl_up(L2[tr][3], 1, 64);
  }
  if (lane == 63) {
#pragma unroll
    for (int tr = 2; tr < 8; ++tr) L2R[tr] = (t2 < 255) ? eB0[wv + 1][tr-2] : 0.f;
  }
  if (lane == 0) {
#pragma unroll
    for (int tr = 2; tr < 8; ++tr) L2L[tr] = (t2 > 0) ? eB3[wv - 1][tr-2] : 0.f;
  }

  // ---- level 3 on output rows 3..6 + writes ----
#pragma unroll
  for (int tr = 3; tr < 7; ++tr) {
    int r = r0 - 3 + tr;
    float q[4];
    sten_q4(L2[tr-1], L2[tr], L2[tr+1], L2L[tr], L2L[tr+1], L2R[tr], L2R[tr-1], r, t2, q);
    float x3[4];
#pragma unroll
    for (int k = 0; k < 4; ++k) {
      float m = L2[tr][k];
      x3[k] = m + c1c * (m - L1[tr][k]) + c2c * (BB[tr-1][k] - q[k]);
    }
    *(float4*)(Op2 + r * GSZ + j0) = make_float4(L2[tr][0], L2[tr][1], L2[tr][2], L2[tr][3]);
    *(float4*)(Op3 + r * GSZ + j0) = make_float4(x3[0], x3[1], x3[2], x3[3]);
  }
}

// ---------- faces + verts (validated round 10) ----------
__device__ __forceinline__ void face_cf(float t0x, float t0y, float t0z,
    float t1x, float t1y, float t1z, float b0x, float b0y, float b0z,
    float* cen, float* fnv) {
  const float third = 1.0f / 3.0f;
  cen[0] = (t0x + t1x + b0x) * third;
  cen[1] = (t0y + t1y + b0y) * third;
  cen[2] = (t0z + t1z + b0z) * third;
  float ax = t1x - t0x, ay = t1y - t0y, az = t1z - t0z;
  float bx = b0x - t0x, by = b0y - t0y, bz = b0z - t0z;
  float cx = ay * bz - az * by;
  float cy = az * bx - ax * bz;
  float cz = ax * by - ay * bx;
  float inv = 1.0f / fmaxf(sqrtf(cx * cx + cy * cy + cz * cz), 1e-12f);
  fnv[0] = cx * inv; fnv[1] = cy * inv; fnv[2] = cz * inv;
}

__global__ __launch_bounds__(NTHR) void k_facesverts(const float* __restrict__ xp,
    float* __restrict__ verts, float* __restrict__ cen, float* __restrict__ fn) {
  int ci = blockIdx.x;           // 0..1022
  int t  = threadIdx.x;
  const float* Ps[3] = { xp, xp + NV, xp + 2 * NV };
  int c0 = t << 2;
  int bT = (ci << 10) + c0, bB = bT + GSZ;
  bool full = (t < 255);
  float T[3][5], B[3][5];
#pragma unroll
  for (int p = 0; p < 3; ++p) {
    float4 a = *(const float4*)(Ps[p] + bT);
    T[p][0] = a.x; T[p][1] = a.y; T[p][2] = a.z; T[p][3] = a.w;
    T[p][4] = full ? Ps[p][bT + 4] : 0.f;
    float4 b = *(const float4*)(Ps[p] + bB);
    B[p][0] = b.x; B[p][1] = b.y; B[p][2] = b.z; B[p][3] = b.w;
    B[p][4] = full ? Ps[p][bB + 4] : 0.f;
  }
  {
    int vtx = bT;
    *(float4*)(verts + 3 * vtx)     = make_float4(T[0][0], T[1][0], T[2][0], T[0][1]);
    *(float4*)(verts + 3 * vtx + 4) = make_float4(T[1][1], T[2][1], T[0][2], T[1][2]);
    *(float4*)(verts + 3 * vtx + 8) = make_float4(T[2][2], T[0][3], T[1][3], T[2][3]);
    if (ci == GSZ - 2) {
      int v2 = bB;
      *(float4*)(verts + 3 * v2)     = make_float4(B[0][0], B[1][0], B[2][0], B[0][1]);
      *(float4*)(verts + 3 * v2 + 4) = make_float4(B[1][1], B[2][1], B[0][2], B[1][2]);
      *(float4*)(verts + 3 * v2 + 8) = make_float4(B[2][2], B[0][3], B[1][3], B[2][3]);
    }
  }
  float c1[12], f1[12], c2[12], f2[12];
#pragma unroll
  for (int k = 0; k < 4; ++k) {
    face_cf(T[0][k], T[1][k], T[2][k], T[0][k+1], T[1][k+1], T[2][k+1],
            B[0][k], B[1][k], B[2][k], &c1[3*k], &f1[3*k]);
    face_cf(T[0][k+1], T[1][k+1], T[2][k+1], B[0][k+1], B[1][k+1], B[2][k+1],
            B[0][k], B[1][k], B[2][k], &c2[3*k], &f2[3*k]);
  }
  size_t fb1 = 3 * ((size_t)ci * (GSZ - 1) + c0);
  size_t fb2 = fb1 + 3 * (size_t)FH;
  if (full) {
#pragma unroll
    for (int w = 0; w < 3; ++w) {
      *(f4u*)(cen + fb1 + 4*w) = (f4u){ c1[4*w], c1[4*w+1], c1[4*w+2], c1[4*w+3] };
      *(f4u*)(fn  + fb1 + 4*w) = (f4u){ f1[4*w], f1[4*w+1], f1[4*w+2], f1[4*w+3] };
      *(f4u*)(cen + fb2 + 4*w) = (f4u){ c2[4*w], c2[4*w+1], c2[4*w+2], c2[4*w+3] };
      *(f4u*)(fn  + fb2 + 4*w) = (f4u){ f2[4*w], f2[4*w+1], f2[4*w+2], f2[4*w+3] };
    }
  } else {
    for (int e = 0; e < 9; ++e) {
      cen[fb1 + e] = c1[e]; fn[fb1 + e] = f1[e];
      cen[fb2 + e] = c2[e]; fn[fb2 + e] = f2[e];
    }
  }
}

// ---------- per-vertex normal ----------
__global__ __launch_bounds__(256) void k_vn(const float* __restrict__ fn,
    float* __restrict__ vn) {
  int t = blockIdx.x * 256 + threadIdx.x;
  int i = t >> 10, j = t & (GSZ - 1);
  float s0 = 0.f, s1 = 0.f, s2 = 0.f;
  bool iN = (i >= 1), iS = (i <= GSZ-2), jW = (j >= 1), jE = (j <= GSZ-2);
  int rowi = i * (GSZ-1);
#define ADD(fidx) { int f_ = (fidx); s0 += fn[3*f_]; s1 += fn[3*f_+1]; s2 += fn[3*f_+2]; }
  if (iS && jE) ADD(rowi + j);
  if (iS && jW) ADD(rowi + j - 1);
  if (iN && jE) ADD(rowi - (GSZ-1) + j);
  if (iS && jW) ADD(FH + rowi + j - 1);
  if (iN && jW) ADD(FH + rowi - (GSZ-1) + j - 1);
  if (iN && jE) ADD(FH + rowi - (GSZ-1) + j);
#undef ADD
  float nrm = sqrtf(s0*s0 + s1*s1 + s2*s2);
  float inv = 1.0f / fmaxf(nrm, 1e-12f);
  vn[3*t] = s0*inv; vn[3*t+1] = s1*inv; vn[3*t+2] = s2*inv;
}

extern "C" void kernel_launch(void* const* d_in, const int* in_sizes, int n_in,
                              void* d_out, int out_size, void* d_ws, size_t ws_size,
                              hipStream_t stream) {
  const float* u = (const float*)d_in[0];
  float* out = (float*)d_out;

  float* verts = out;
  float* cen   = out + O1;
  float* fn    = out + O2;
  float* vn    = out + O3;

  // Scratch (all disjoint):
  //   Aa  = verts region [0,3NV); bpl/Bb/Cc inside cen+fn (9NV < 6NF);
  //   Dv  = vn region — final x lands here, k_vn overwrites last.
  float* Aa  = out;
  float* bpl = out + O1;
  float* Bb  = out + O1 + 3 * (size_t)NV;
  float* Cc  = out + O1 + 6 * (size_t)NV;
  float* Dv  = out + O3;

  // Chebyshev, host-precomputed coefficients, 3 steps/launch.
  // Parity: p=(NFUSED-1-j)&1; p==0 -> read (Aa,Bb) write (Cc,Dv);
  // p==1 -> read (Cc,Dv) write (Aa,Bb). j=0 reads u (folded init).
  double s1 = CH_THETA / CH_DELTA;
  double rho_p = 1.0 / s1;
  float cc[6];
  int ci = 0, j = 0;
  for (int k = 1; k <= 3 * NFUSED; ++k) {
    double rho = 1.0 / (2.0 * s1 - rho_p);
    cc[2*ci]   = (float)(rho * rho_p);
    cc[2*ci+1] = (float)(2.0 * rho / CH_DELTA);
    rho_p = rho;
    if (++ci == 3) {
      int p = (NFUSED - 1 - j) & 1;
      float* o2_ = p ? Aa : Cc;
      float* o3_ = p ? Bb : Dv;
      if (j == 0) {
        k_cheb3_first<<<dim3(768), dim3(256), 0, stream>>>(u, o2_, o3_, bpl,
            cc[0], cc[1], cc[2], cc[3], cc[4], cc[5]);
      } else {
        const float* xp_ = p ? Cc : Aa;
        const float* xs_ = p ? Dv : Bb;
        k_cheb3<<<dim3(768), dim3(256), 0, stream>>>(xs_, xp_, o2_, o3_, bpl,
            cc[0], cc[1], cc[2], cc[3], cc[4], cc[5]);
      }
      ci = 0; ++j;
    }
  }
  // NFUSED=21: last launch j=20 has p=0 -> final x_64 in Dv.

  k_facesverts<<<dim3(GSZ - 1), dim3(NTHR), 0, stream>>>(Dv, verts, cen, fn);
  k_vn<<<dim3(NV / 256), dim3(256), 0, stream>>>(fn, vn);
}